// Round 1
// baseline (1722.508 us; speedup 1.0000x reference)
//
#include <hip/hip_runtime.h>

// Problem constants (fixed by the reference)
#define N_NODES 100000
#define N_EDGES 3200000
#define F_IN 32
#define F_EDGE 16
#define H 27

// ---------------------------------------------------------------------------
// deg[n] = 1 (self loop); then += 1 per incoming edge; then deg := rsqrt(deg)
// ---------------------------------------------------------------------------
__global__ __launch_bounds__(256) void k_deg_init(float* __restrict__ deg) {
    int i = blockIdx.x * 256 + threadIdx.x;
    if (i < N_NODES) deg[i] = 1.0f;
}

__global__ __launch_bounds__(256) void k_deg_count(const int* __restrict__ ei,
                                                   float* __restrict__ deg) {
    int e = blockIdx.x * 256 + threadIdx.x;
    if (e < N_EDGES) atomicAdd(&deg[ei[N_EDGES + e]], 1.0f);
}

__global__ __launch_bounds__(256) void k_dinv(float* __restrict__ deg) {
    int i = blockIdx.x * 256 + threadIdx.x;
    if (i < N_NODES) deg[i] = rsqrtf(deg[i]);
}

// ---------------------------------------------------------------------------
// Layer-1 pre: g1[n] = (x[n] @ W1) * dinv[n]; bufA = g1; bufB = g1 (self loop)
// ---------------------------------------------------------------------------
__global__ __launch_bounds__(256) void k_l1pre(const float* __restrict__ x,
                                               const float* __restrict__ W1,
                                               const float* __restrict__ dinv,
                                               float* __restrict__ bufA,
                                               float* __restrict__ bufB) {
    __shared__ float w[F_IN * H];
    for (int i = threadIdx.x; i < F_IN * H; i += 256) w[i] = W1[i];
    __syncthreads();
    int n = blockIdx.x * 256 + threadIdx.x;
    if (n >= N_NODES) return;

    float xv[F_IN];
    const float4* xp = (const float4*)(x + (long long)n * F_IN);
#pragma unroll
    for (int j = 0; j < F_IN / 4; j++) {
        float4 v = xp[j];
        xv[4 * j] = v.x; xv[4 * j + 1] = v.y; xv[4 * j + 2] = v.z; xv[4 * j + 3] = v.w;
    }
    float di = dinv[n];
    long long base = (long long)n * H;
#pragma unroll
    for (int j = 0; j < H; j++) {
        float acc = 0.f;
#pragma unroll
        for (int k = 0; k < F_IN; k++) acc += xv[k] * w[k * H + j];
        acc *= di;
        bufA[base + j] = acc;
        bufB[base + j] = acc;
    }
}

// ---------------------------------------------------------------------------
// Edge scatter: bufB[col] += bufA[row]  (thread = (edge, feature); 32 lanes/edge)
// ---------------------------------------------------------------------------
__global__ __launch_bounds__(256) void k_scatter(const int* __restrict__ ei,
                                                 const float* __restrict__ src,
                                                 float* __restrict__ dst) {
    long long gid = (long long)blockIdx.x * 256 + threadIdx.x;
    int e = (int)(gid >> 5);
    int h = (int)(gid & 31);
    if (e >= N_EDGES || h >= H) return;
    int r = ei[e];
    int c = ei[N_EDGES + e];
    atomicAdd(&dst[(long long)c * H + h], src[(long long)r * H + h]);
}

// ---------------------------------------------------------------------------
// Layer-1 post + layer-2 pre:
//   o1 = relu(b1 + dinv*agg1); g2 = (o1 @ W2) * dinv; bufA = bufB = g2
// ---------------------------------------------------------------------------
__global__ __launch_bounds__(256) void k_l1post(const float* __restrict__ W2,
                                                const float* __restrict__ b1,
                                                const float* __restrict__ dinv,
                                                float* __restrict__ bufA,
                                                float* __restrict__ bufB) {
    __shared__ float w[H * H];
    __shared__ float bs[H];
    for (int i = threadIdx.x; i < H * H; i += 256) w[i] = W2[i];
    if (threadIdx.x < H) bs[threadIdx.x] = b1[threadIdx.x];
    __syncthreads();
    int n = blockIdx.x * 256 + threadIdx.x;
    if (n >= N_NODES) return;

    float di = dinv[n];
    long long base = (long long)n * H;
    float o1[H];
#pragma unroll
    for (int k = 0; k < H; k++) {
        float v = bs[k] + di * bufB[base + k];
        o1[k] = v > 0.f ? v : 0.f;
    }
#pragma unroll
    for (int j = 0; j < H; j++) {
        float acc = 0.f;
#pragma unroll
        for (int k = 0; k < H; k++) acc += o1[k] * w[k * H + j];
        acc *= di;
        bufA[base + j] = acc;
        bufB[base + j] = acc;
    }
}

// ---------------------------------------------------------------------------
// Final node features: h[n] = b2 + dinv[n] * agg2[n]   (element-parallel)
// ---------------------------------------------------------------------------
__global__ __launch_bounds__(256) void k_nodefin(const float* __restrict__ b2,
                                                 const float* __restrict__ dinv,
                                                 const float* __restrict__ bufB,
                                                 float* __restrict__ bufA) {
    int i = blockIdx.x * 256 + threadIdx.x;
    if (i >= N_NODES * H) return;
    int n = i / H;
    int j = i - n * H;
    bufA[i] = b2[j] + dinv[n] * bufB[i];
}

// ---------------------------------------------------------------------------
// Edge head: ef = relu(ea@ew1+eb1)@ew2+eb2;
//            out[e] = fcb + h[row]·fcw[0:27] + h[col]·fcw[27:54] + ef·fcw[54:81]
// ---------------------------------------------------------------------------
__global__ __launch_bounds__(256) void k_edge(const int* __restrict__ ei,
                                              const float* __restrict__ ea,
                                              const float* __restrict__ ew1,
                                              const float* __restrict__ eb1,
                                              const float* __restrict__ ew2,
                                              const float* __restrict__ eb2,
                                              const float* __restrict__ fcw,
                                              const float* __restrict__ fcb,
                                              const float* __restrict__ hfin,
                                              float* __restrict__ out) {
    __shared__ float w1s[F_EDGE * H];
    __shared__ float w2s[H * H];
    __shared__ float fws[3 * H];
    __shared__ float b1s[H], b2s[H];
    __shared__ float fcbs;
    for (int i = threadIdx.x; i < F_EDGE * H; i += 256) w1s[i] = ew1[i];
    for (int i = threadIdx.x; i < H * H; i += 256) w2s[i] = ew2[i];
    if (threadIdx.x < 3 * H) fws[threadIdx.x] = fcw[threadIdx.x];
    if (threadIdx.x < H) { b1s[threadIdx.x] = eb1[threadIdx.x]; b2s[threadIdx.x] = eb2[threadIdx.x]; }
    if (threadIdx.x == 0) fcbs = fcb[0];
    __syncthreads();
    int e = blockIdx.x * 256 + threadIdx.x;
    if (e >= N_EDGES) return;

    float a[F_EDGE];
    const float4* ap = (const float4*)(ea + (long long)e * F_EDGE);
#pragma unroll
    for (int j = 0; j < F_EDGE / 4; j++) {
        float4 v = ap[j];
        a[4 * j] = v.x; a[4 * j + 1] = v.y; a[4 * j + 2] = v.z; a[4 * j + 3] = v.w;
    }

    float t[H];
#pragma unroll
    for (int j = 0; j < H; j++) {
        float acc = b1s[j];
#pragma unroll
        for (int k = 0; k < F_EDGE; k++) acc += a[k] * w1s[k * H + j];
        t[j] = acc > 0.f ? acc : 0.f;
    }

    int r = ei[e];
    int c = ei[N_EDGES + e];
    const float* hr = hfin + (long long)r * H;
    const float* hc = hfin + (long long)c * H;

    float acc = fcbs;
#pragma unroll
    for (int j = 0; j < H; j++) {
        float ef = b2s[j];
#pragma unroll
        for (int k = 0; k < H; k++) ef += t[k] * w2s[k * H + j];
        acc += ef * fws[54 + j];
    }
#pragma unroll
    for (int j = 0; j < H; j++) acc += hr[j] * fws[j] + hc[j] * fws[27 + j];

    out[e] = acc;
}

// ---------------------------------------------------------------------------
extern "C" void kernel_launch(void* const* d_in, const int* in_sizes, int n_in,
                              void* d_out, int out_size, void* d_ws, size_t ws_size,
                              hipStream_t stream) {
    const float* x   = (const float*)d_in[0];
    const int*   ei  = (const int*)d_in[1];
    const float* ea  = (const float*)d_in[2];
    const float* W1  = (const float*)d_in[3];
    const float* b1  = (const float*)d_in[4];
    const float* W2  = (const float*)d_in[5];
    const float* b2  = (const float*)d_in[6];
    const float* ew1 = (const float*)d_in[7];
    const float* eb1 = (const float*)d_in[8];
    const float* ew2 = (const float*)d_in[9];
    const float* eb2 = (const float*)d_in[10];
    const float* fcw = (const float*)d_in[11];
    const float* fcb = (const float*)d_in[12];
    float* out = (float*)d_out;

    // Workspace layout: dinv [N] | bufA [N*H] | bufB [N*H]  (~22 MB total)
    float* ws   = (float*)d_ws;
    float* dinv = ws;
    float* bufA = ws + N_NODES;
    float* bufB = bufA + (size_t)N_NODES * H;

    const int nb_nodes = (N_NODES + 255) / 256;
    const int nb_edges = (N_EDGES + 255) / 256;
    const int nb_scat  = (int)(((long long)N_EDGES * 32 + 255) / 256);
    const int nb_nh    = (N_NODES * H + 255) / 256;

    k_deg_init<<<nb_nodes, 256, 0, stream>>>(dinv);
    k_deg_count<<<nb_edges, 256, 0, stream>>>(ei, dinv);
    k_dinv<<<nb_nodes, 256, 0, stream>>>(dinv);

    // Layer 1
    k_l1pre<<<nb_nodes, 256, 0, stream>>>(x, W1, dinv, bufA, bufB);
    k_scatter<<<nb_scat, 256, 0, stream>>>(ei, bufA, bufB);

    // Layer 1 epilogue + layer 2 input
    k_l1post<<<nb_nodes, 256, 0, stream>>>(W2, b1, dinv, bufA, bufB);
    k_scatter<<<nb_scat, 256, 0, stream>>>(ei, bufA, bufB);

    // Final node features into bufA
    k_nodefin<<<nb_nh, 256, 0, stream>>>(b2, dinv, bufB, bufA);

    // Edge MLP + scorer
    k_edge<<<nb_edges, 256, 0, stream>>>(ei, ea, ew1, eb1, ew2, eb2, fcw, fcb, bufA, out);
}

// Round 2
// 1352.584 us; speedup vs baseline: 1.2735x; 1.2735x over previous
//
#include <hip/hip_runtime.h>

// Problem constants (fixed by the reference)
#define N_NODES 100000
#define N_EDGES 3200000
#define F_IN 32
#define F_EDGE 16
#define H 27

// ---------------------------------------------------------------------------
// deg[n] = 1 (self loop); += 1 per incoming edge; deg := rsqrt(deg)
// ---------------------------------------------------------------------------
__global__ __launch_bounds__(256) void k_deg_init(float* __restrict__ deg) {
    int i = blockIdx.x * 256 + threadIdx.x;
    if (i < N_NODES) deg[i] = 1.0f;
}

__global__ __launch_bounds__(256) void k_deg_count(const int* __restrict__ ei,
                                                   float* __restrict__ deg) {
    int e = blockIdx.x * 256 + threadIdx.x;
    if (e < N_EDGES) atomicAdd(&deg[ei[N_EDGES + e]], 1.0f);
}

__global__ __launch_bounds__(256) void k_dinv(float* __restrict__ deg) {
    int i = blockIdx.x * 256 + threadIdx.x;
    if (i < N_NODES) deg[i] = rsqrtf(deg[i]);
}

// ---------------------------------------------------------------------------
// Layer-1 pre: g1[n] = (x[n] @ W1) * dinv[n]; bufA = g1; bufB = g1 (self loop)
// ---------------------------------------------------------------------------
__global__ __launch_bounds__(256) void k_l1pre(const float* __restrict__ x,
                                               const float* __restrict__ W1,
                                               const float* __restrict__ dinv,
                                               float* __restrict__ bufA,
                                               float* __restrict__ bufB) {
    __shared__ float w[F_IN * H];
    for (int i = threadIdx.x; i < F_IN * H; i += 256) w[i] = W1[i];
    __syncthreads();
    int n = blockIdx.x * 256 + threadIdx.x;
    if (n >= N_NODES) return;

    float xv[F_IN];
    const float4* xp = (const float4*)(x + (long long)n * F_IN);
#pragma unroll
    for (int j = 0; j < F_IN / 4; j++) {
        float4 v = xp[j];
        xv[4 * j] = v.x; xv[4 * j + 1] = v.y; xv[4 * j + 2] = v.z; xv[4 * j + 3] = v.w;
    }
    float di = dinv[n];
    long long base = (long long)n * H;
#pragma unroll
    for (int j = 0; j < H; j++) {
        float acc = 0.f;
#pragma unroll
        for (int k = 0; k < F_IN; k++) acc += xv[k] * w[k * H + j];
        acc *= di;
        bufA[base + j] = acc;
        bufB[base + j] = acc;
    }
}

// ---------------------------------------------------------------------------
// Layer-1 edge scatter (27 floats/edge): bufB[col] += bufA[row]
// thread = (edge, feature); 32 lanes per edge
// ---------------------------------------------------------------------------
__global__ __launch_bounds__(256) void k_scatter27(const int* __restrict__ ei,
                                                   const float* __restrict__ src,
                                                   float* __restrict__ dst) {
    long long gid = (long long)blockIdx.x * 256 + threadIdx.x;
    int e = (int)(gid >> 5);
    int h = (int)(gid & 31);
    if (e >= N_EDGES || h >= H) return;
    int r = ei[e];
    int c = ei[N_EDGES + e];
    atomicAdd(&dst[(long long)c * H + h], src[(long long)r * H + h]);
}

// ---------------------------------------------------------------------------
// Layer-1 post + layer-2 GEMM + head collapse:
//   o1 = relu(b1 + dinv*agg1); g2 = (o1@W2)*dinv
//   s0[n] = g2·fcw[0:27]; s1[n] = g2·fcw[27:54]; agg0/agg1 init with self-loop
// ---------------------------------------------------------------------------
__global__ __launch_bounds__(256) void k_l1post(const float* __restrict__ W2,
                                                const float* __restrict__ b1,
                                                const float* __restrict__ fcw,
                                                const float* __restrict__ dinv,
                                                const float* __restrict__ bufB,
                                                float* __restrict__ s0,
                                                float* __restrict__ s1,
                                                float* __restrict__ agg0,
                                                float* __restrict__ agg1) {
    __shared__ float w[H * H];
    __shared__ float bs[H];
    __shared__ float f0[H], f1[H];
    for (int i = threadIdx.x; i < H * H; i += 256) w[i] = W2[i];
    if (threadIdx.x < H) {
        bs[threadIdx.x] = b1[threadIdx.x];
        f0[threadIdx.x] = fcw[threadIdx.x];
        f1[threadIdx.x] = fcw[H + threadIdx.x];
    }
    __syncthreads();
    int n = blockIdx.x * 256 + threadIdx.x;
    if (n >= N_NODES) return;

    float di = dinv[n];
    long long base = (long long)n * H;
    float o1[H];
#pragma unroll
    for (int k = 0; k < H; k++) {
        float v = bs[k] + di * bufB[base + k];
        o1[k] = v > 0.f ? v : 0.f;
    }
    float r0 = 0.f, r1 = 0.f;
#pragma unroll
    for (int j = 0; j < H; j++) {
        float g = 0.f;
#pragma unroll
        for (int k = 0; k < H; k++) g += o1[k] * w[k * H + j];
        g *= di;
        r0 += g * f0[j];
        r1 += g * f1[j];
    }
    s0[n] = r0; s1[n] = r1;
    agg0[n] = r0; agg1[n] = r1;  // self-loop contribution
}

// ---------------------------------------------------------------------------
// Layer-2 scatter, collapsed to scalars: agg{0,1}[col] += s{0,1}[row]
// ---------------------------------------------------------------------------
__global__ __launch_bounds__(256) void k_scatter2(const int* __restrict__ ei,
                                                  const float* __restrict__ s0,
                                                  const float* __restrict__ s1,
                                                  float* __restrict__ agg0,
                                                  float* __restrict__ agg1) {
    int e = blockIdx.x * 256 + threadIdx.x;
    if (e >= N_EDGES) return;
    int r = ei[e];
    int c = ei[N_EDGES + e];
    atomicAdd(&agg0[c], s0[r]);
    atomicAdd(&agg1[c], s1[r]);
}

// ---------------------------------------------------------------------------
// Per-node head scalars: pr[n] = b2·f0 + dinv*agg0; pc[n] = b2·f1 + dinv*agg1
// ---------------------------------------------------------------------------
__global__ __launch_bounds__(256) void k_nodehead(const float* __restrict__ b2,
                                                  const float* __restrict__ fcw,
                                                  const float* __restrict__ dinv,
                                                  const float* __restrict__ agg0,
                                                  const float* __restrict__ agg1,
                                                  float* __restrict__ pr,
                                                  float* __restrict__ pc) {
    int n = blockIdx.x * 256 + threadIdx.x;
    if (n >= N_NODES) return;
    float d0 = 0.f, d1 = 0.f;
#pragma unroll
    for (int j = 0; j < H; j++) {
        float b = b2[j];
        d0 += b * fcw[j];
        d1 += b * fcw[H + j];
    }
    float di = dinv[n];
    pr[n] = d0 + di * agg0[n];
    pc[n] = d1 + di * agg1[n];
}

// ---------------------------------------------------------------------------
// Tiny prep: v[k] = Σ_j ew2[k][j]*fcw[54+j];  vbuf[27] = fcb + Σ_j eb2[j]*fcw[54+j]
// ---------------------------------------------------------------------------
__global__ void k_prep(const float* __restrict__ ew2,
                       const float* __restrict__ eb2,
                       const float* __restrict__ fcw,
                       const float* __restrict__ fcb,
                       float* __restrict__ vbuf) {
    int k = threadIdx.x;
    if (k < H) {
        float acc = 0.f;
#pragma unroll
        for (int j = 0; j < H; j++) acc += ew2[k * H + j] * fcw[2 * H + j];
        vbuf[k] = acc;
    } else if (k == H) {
        float acc = fcb[0];
#pragma unroll
        for (int j = 0; j < H; j++) acc += eb2[j] * fcw[2 * H + j];
        vbuf[H] = acc;
    }
}

// ---------------------------------------------------------------------------
// Edge head, collapsed:
//   out[e] = c0 + Σ_k relu(b1e[k] + ea[e]·w1[:,k]) * v[k] + pr[row] + pc[col]
// 4 edges per thread so each LDS weight-column read is reused 4×.
// ---------------------------------------------------------------------------
__global__ __launch_bounds__(256) void k_edge_final(const int* __restrict__ ei,
                                                    const float* __restrict__ ea,
                                                    const float* __restrict__ ew1,
                                                    const float* __restrict__ eb1,
                                                    const float* __restrict__ vbuf,
                                                    const float* __restrict__ pr,
                                                    const float* __restrict__ pc,
                                                    float* __restrict__ out) {
    __shared__ float w1t[H * F_EDGE];  // transposed: [k][m], column k contiguous
    __shared__ float b1s[H];
    __shared__ float vs[H];
    __shared__ float c0s;
    for (int i = threadIdx.x; i < H * F_EDGE; i += 256) {
        int k = i >> 4, m = i & 15;
        w1t[i] = ew1[m * H + k];
    }
    if (threadIdx.x < H) { b1s[threadIdx.x] = eb1[threadIdx.x]; vs[threadIdx.x] = vbuf[threadIdx.x]; }
    if (threadIdx.x == 0) c0s = vbuf[H];
    __syncthreads();

    long long t = (long long)blockIdx.x * 256 + threadIdx.x;
    long long e0 = t * 4;
    if (e0 >= N_EDGES) return;

    // Load 4 edges' attributes (64 floats, contiguous 256 B per thread)
    float a[4][F_EDGE];
#pragma unroll
    for (int i = 0; i < 4; i++) {
        const float4* p = (const float4*)(ea + (e0 + i) * F_EDGE);
#pragma unroll
        for (int j = 0; j < F_EDGE / 4; j++) {
            float4 v = p[j];
            a[i][4 * j] = v.x; a[i][4 * j + 1] = v.y; a[i][4 * j + 2] = v.z; a[i][4 * j + 3] = v.w;
        }
    }

    float c0 = c0s;
    float acc[4] = {c0, c0, c0, c0};
    const float4* w1v = (const float4*)w1t;
#pragma unroll
    for (int k = 0; k < H; k++) {
        float4 wa = w1v[k * 4 + 0];
        float4 wb = w1v[k * 4 + 1];
        float4 wc = w1v[k * 4 + 2];
        float4 wd = w1v[k * 4 + 3];
        float bk = b1s[k];
        float vk = vs[k];
#pragma unroll
        for (int i = 0; i < 4; i++) {
            float s = bk;
            s += a[i][0] * wa.x + a[i][1] * wa.y + a[i][2] * wa.z + a[i][3] * wa.w;
            s += a[i][4] * wb.x + a[i][5] * wb.y + a[i][6] * wb.z + a[i][7] * wb.w;
            s += a[i][8] * wc.x + a[i][9] * wc.y + a[i][10] * wc.z + a[i][11] * wc.w;
            s += a[i][12] * wd.x + a[i][13] * wd.y + a[i][14] * wd.z + a[i][15] * wd.w;
            acc[i] += (s > 0.f ? s : 0.f) * vk;
        }
    }

    float res[4];
#pragma unroll
    for (int i = 0; i < 4; i++) {
        int r = ei[e0 + i];
        int c = ei[N_EDGES + e0 + i];
        res[i] = acc[i] + pr[r] + pc[c];
    }
    *(float4*)(out + e0) = *(float4*)res;
}

// ---------------------------------------------------------------------------
extern "C" void kernel_launch(void* const* d_in, const int* in_sizes, int n_in,
                              void* d_out, int out_size, void* d_ws, size_t ws_size,
                              hipStream_t stream) {
    const float* x   = (const float*)d_in[0];
    const int*   ei  = (const int*)d_in[1];
    const float* ea  = (const float*)d_in[2];
    const float* W1  = (const float*)d_in[3];
    const float* b1  = (const float*)d_in[4];
    const float* W2  = (const float*)d_in[5];
    const float* b2  = (const float*)d_in[6];
    const float* ew1 = (const float*)d_in[7];
    const float* eb1 = (const float*)d_in[8];
    const float* ew2 = (const float*)d_in[9];
    const float* eb2 = (const float*)d_in[10];
    const float* fcw = (const float*)d_in[11];
    const float* fcb = (const float*)d_in[12];
    float* out = (float*)d_out;

    // Workspace layout (floats): dinv [N] | bufA [N*H] | bufB [N*H]
    // After scatter1, bufA region is dead → overlay s0/s1/agg0/agg1/pr/pc/vbuf.
    float* ws   = (float*)d_ws;
    float* dinv = ws;
    float* bufA = ws + N_NODES;
    float* bufB = bufA + (size_t)N_NODES * H;

    float* s0   = bufA;
    float* s1   = bufA + (size_t)N_NODES;
    float* agg0 = bufA + (size_t)2 * N_NODES;
    float* agg1 = bufA + (size_t)3 * N_NODES;
    float* pr   = bufA + (size_t)4 * N_NODES;
    float* pc   = bufA + (size_t)5 * N_NODES;
    float* vbuf = bufA + (size_t)6 * N_NODES;  // 28 floats

    const int nb_nodes = (N_NODES + 255) / 256;
    const int nb_edges = (N_EDGES + 255) / 256;
    const int nb_scat  = (int)(((long long)N_EDGES * 32 + 255) / 256);
    const int nb_e4    = (N_EDGES / 4 + 255) / 256;  // 3125 exact

    k_deg_init<<<nb_nodes, 256, 0, stream>>>(dinv);
    k_deg_count<<<nb_edges, 256, 0, stream>>>(ei, dinv);
    k_dinv<<<nb_nodes, 256, 0, stream>>>(dinv);

    // Layer 1
    k_l1pre<<<nb_nodes, 256, 0, stream>>>(x, W1, dinv, bufA, bufB);
    k_scatter27<<<nb_scat, 256, 0, stream>>>(ei, bufA, bufB);

    // Layer-1 epilogue + layer-2 GEMM + head collapse to per-node scalars
    k_l1post<<<nb_nodes, 256, 0, stream>>>(W2, b1, fcw, dinv, bufB, s0, s1, agg0, agg1);
    k_scatter2<<<nb_edges, 256, 0, stream>>>(ei, s0, s1, agg0, agg1);
    k_nodehead<<<nb_nodes, 256, 0, stream>>>(b2, fcw, dinv, agg0, agg1, pr, pc);

    // Edge head
    k_prep<<<1, 64, 0, stream>>>(ew2, eb2, fcw, fcb, vbuf);
    k_edge_final<<<nb_e4, 256, 0, stream>>>(ei, ea, ew1, eb1, vbuf, pr, pc, out);
}

// Round 3
// 972.348 us; speedup vs baseline: 1.7715x; 1.3910x over previous
//
#include <hip/hip_runtime.h>

// Problem constants (fixed by the reference)
#define N_NODES 100000
#define N_EDGES 3200000
#define F_IN 32
#define F_EDGE 16
#define H 27
#define PAD 32          // node-feature row stride (128 B, cache-line aligned)
#define NB_NODES ((N_NODES + 255) / 256)   // 391

// ---------------------------------------------------------------------------
// CSR build: cnt=0; cnt[c]++ per edge; exclusive scan -> ptr; fill csr by dest
// ---------------------------------------------------------------------------
__global__ __launch_bounds__(256) void k_zero(int* __restrict__ cnt) {
    int i = blockIdx.x * 256 + threadIdx.x;
    if (i < N_NODES) cnt[i] = 0;
}

__global__ __launch_bounds__(256) void k_count(const int* __restrict__ ei,
                                               int* __restrict__ cnt) {
    int e = blockIdx.x * 256 + threadIdx.x;
    if (e < N_EDGES) atomicAdd(&cnt[ei[N_EDGES + e]], 1);
}

__global__ __launch_bounds__(256) void k_blocksum(const int* __restrict__ cnt,
                                                  int* __restrict__ bsum) {
    __shared__ int sd[256];
    int tid = threadIdx.x;
    int i = blockIdx.x * 256 + tid;
    sd[tid] = (i < N_NODES) ? cnt[i] : 0;
    __syncthreads();
    for (int s = 128; s > 0; s >>= 1) {
        if (tid < s) sd[tid] += sd[tid + s];
        __syncthreads();
    }
    if (tid == 0) bsum[blockIdx.x] = sd[0];
}

__global__ __launch_bounds__(512) void k_scan_bsums(const int* __restrict__ bsum,
                                                    int* __restrict__ bpre) {
    __shared__ int sb[NB_NODES];
    int tid = threadIdx.x;
    if (tid < NB_NODES) sb[tid] = bsum[tid];
    __syncthreads();
    if (tid == 0) {
        int run = 0;
        for (int b = 0; b < NB_NODES; b++) { int v = sb[b]; sb[b] = run; run += v; }
    }
    __syncthreads();
    if (tid < NB_NODES) bpre[tid] = sb[tid];
}

__global__ __launch_bounds__(256) void k_scan_final(const int* __restrict__ cnt,
                                                    const int* __restrict__ bpre,
                                                    int* __restrict__ ptr,
                                                    int* __restrict__ fillpos) {
    __shared__ int sd[256];
    int tid = threadIdx.x;
    int i = blockIdx.x * 256 + tid;
    int v = (i < N_NODES) ? cnt[i] : 0;
    sd[tid] = v;
    __syncthreads();
    for (int off = 1; off < 256; off <<= 1) {  // Hillis-Steele inclusive scan
        int t = (tid >= off) ? sd[tid - off] : 0;
        __syncthreads();
        sd[tid] += t;
        __syncthreads();
    }
    if (i < N_NODES) {
        int excl = bpre[blockIdx.x] + sd[tid] - v;
        ptr[i] = excl;
        fillpos[i] = excl;
        if (i == N_NODES - 1) ptr[N_NODES] = excl + v;  // == N_EDGES
    }
}

__global__ __launch_bounds__(256) void k_fill(const int* __restrict__ ei,
                                              int* __restrict__ fillpos,
                                              int* __restrict__ csr) {
    int e = blockIdx.x * 256 + threadIdx.x;
    if (e >= N_EDGES) return;
    int r = ei[e];
    int c = ei[N_EDGES + e];
    int pos = atomicAdd(&fillpos[c], 1);
    csr[pos] = r;
}

// ---------------------------------------------------------------------------
// dinv[n] = rsqrt(1 + indegree)
// ---------------------------------------------------------------------------
__global__ __launch_bounds__(256) void k_dinv(const int* __restrict__ cnt,
                                              float* __restrict__ dinv) {
    int i = blockIdx.x * 256 + threadIdx.x;
    if (i < N_NODES) dinv[i] = rsqrtf((float)(cnt[i] + 1));
}

// ---------------------------------------------------------------------------
// Layer-1 pre: g1[n] = (x[n] @ W1) * dinv[n]  (row stride PAD)
// ---------------------------------------------------------------------------
__global__ __launch_bounds__(256) void k_l1pre(const float* __restrict__ x,
                                               const float* __restrict__ W1,
                                               const float* __restrict__ dinv,
                                               float* __restrict__ bufA) {
    __shared__ float w[F_IN * H];
    for (int i = threadIdx.x; i < F_IN * H; i += 256) w[i] = W1[i];
    __syncthreads();
    int n = blockIdx.x * 256 + threadIdx.x;
    if (n >= N_NODES) return;

    float xv[F_IN];
    const float4* xp = (const float4*)(x + (long long)n * F_IN);
#pragma unroll
    for (int j = 0; j < F_IN / 4; j++) {
        float4 v = xp[j];
        xv[4 * j] = v.x; xv[4 * j + 1] = v.y; xv[4 * j + 2] = v.z; xv[4 * j + 3] = v.w;
    }
    float di = dinv[n];
    long long base = (long long)n * PAD;
#pragma unroll
    for (int j = 0; j < H; j++) {
        float acc = 0.f;
#pragma unroll
        for (int k = 0; k < F_IN; k++) acc += xv[k] * w[k * H + j];
        bufA[base + j] = acc * di;
    }
}

// ---------------------------------------------------------------------------
// Layer-1 aggregate, PULL: bufB[n] = g1[n] + sum over in-edges g1[src]
// 32 lanes per node; lane = feature. No atomics; src table is LLC-resident.
// ---------------------------------------------------------------------------
__global__ __launch_bounds__(256) void k_gather27(const int* __restrict__ ptr,
                                                  const int* __restrict__ csr,
                                                  const float* __restrict__ bufA,
                                                  float* __restrict__ bufB) {
    int g = blockIdx.x * 256 + threadIdx.x;
    int n = g >> 5;
    int lane = g & 31;
    if (n >= N_NODES) return;
    int p0 = ptr[n], p1 = ptr[n + 1];

    float acc = (lane < H) ? bufA[(long long)n * PAD + lane] : 0.f;  // self loop
    int i = p0;
    while (i < p1) {
        int m = p1 - i; if (m > 32) m = 32;
        int idx = (lane < m) ? csr[i + lane] : 0;   // one coalesced batch load
#pragma unroll 4
        for (int j = 0; j < m; j++) {
            int r = __shfl(idx, j, 32);
            acc += bufA[(long long)r * PAD + lane];  // 2 cache lines per row
        }
        i += m;
    }
    if (lane < H) bufB[(long long)n * PAD + lane] = acc;
}

// ---------------------------------------------------------------------------
// Layer-1 post + layer-2 GEMM + head collapse:
//   o1 = relu(b1 + dinv*agg); g2 = (o1@W2)*dinv
//   s0[n] = g2 . fcw[0:27]; s1[n] = g2 . fcw[27:54]
// ---------------------------------------------------------------------------
__global__ __launch_bounds__(256) void k_l1post(const float* __restrict__ W2,
                                                const float* __restrict__ b1,
                                                const float* __restrict__ fcw,
                                                const float* __restrict__ dinv,
                                                const float* __restrict__ bufB,
                                                float* __restrict__ s0,
                                                float* __restrict__ s1) {
    __shared__ float w[H * H];
    __shared__ float bs[H];
    __shared__ float f0[H], f1[H];
    for (int i = threadIdx.x; i < H * H; i += 256) w[i] = W2[i];
    if (threadIdx.x < H) {
        bs[threadIdx.x] = b1[threadIdx.x];
        f0[threadIdx.x] = fcw[threadIdx.x];
        f1[threadIdx.x] = fcw[H + threadIdx.x];
    }
    __syncthreads();
    int n = blockIdx.x * 256 + threadIdx.x;
    if (n >= N_NODES) return;

    float di = dinv[n];
    long long base = (long long)n * PAD;
    float o1[H];
#pragma unroll
    for (int k = 0; k < H; k++) {
        float v = bs[k] + di * bufB[base + k];
        o1[k] = v > 0.f ? v : 0.f;
    }
    float r0 = 0.f, r1 = 0.f;
#pragma unroll
    for (int j = 0; j < H; j++) {
        float g = 0.f;
#pragma unroll
        for (int k = 0; k < H; k++) g += o1[k] * w[k * H + j];
        g *= di;
        r0 += g * f0[j];
        r1 += g * f1[j];
    }
    s0[n] = r0; s1[n] = r1;
}

// ---------------------------------------------------------------------------
// Tiny prep: vbuf[0:27] = ew2 @ fcw[54:81]; vbuf[27] = fcb + eb2 . fcw[54:81];
//            vbuf[28] = b2 . fcw[0:27];     vbuf[29] = b2 . fcw[27:54]
// ---------------------------------------------------------------------------
__global__ void k_prep(const float* __restrict__ ew2,
                       const float* __restrict__ eb2,
                       const float* __restrict__ b2,
                       const float* __restrict__ fcw,
                       const float* __restrict__ fcb,
                       float* __restrict__ vbuf) {
    int k = threadIdx.x;
    if (k < H) {
        float acc = 0.f;
#pragma unroll
        for (int j = 0; j < H; j++) acc += ew2[k * H + j] * fcw[2 * H + j];
        vbuf[k] = acc;
    } else if (k == H) {
        float acc = fcb[0];
#pragma unroll
        for (int j = 0; j < H; j++) acc += eb2[j] * fcw[2 * H + j];
        vbuf[H] = acc;
    } else if (k == H + 1) {
        float acc = 0.f;
#pragma unroll
        for (int j = 0; j < H; j++) acc += b2[j] * fcw[j];
        vbuf[H + 1] = acc;
    } else if (k == H + 2) {
        float acc = 0.f;
#pragma unroll
        for (int j = 0; j < H; j++) acc += b2[j] * fcw[H + j];
        vbuf[H + 2] = acc;
    }
}

// ---------------------------------------------------------------------------
// Layer-2 aggregate (collapsed to 2 scalars), PULL + head:
//   pr[n] = (b2.f0) + dinv*(s0[n] + sum s0[src]);  pc likewise with s1
// 32 lanes per node, strided accumulate + shuffle reduce. No atomics.
// ---------------------------------------------------------------------------
__global__ __launch_bounds__(256) void k_pull2(const int* __restrict__ ptr,
                                               const int* __restrict__ csr,
                                               const float* __restrict__ s0,
                                               const float* __restrict__ s1,
                                               const float* __restrict__ dinv,
                                               const float* __restrict__ vbuf,
                                               float* __restrict__ pr,
                                               float* __restrict__ pc) {
    int g = blockIdx.x * 256 + threadIdx.x;
    int n = g >> 5;
    int lane = g & 31;
    if (n >= N_NODES) return;
    int p0 = ptr[n], p1 = ptr[n + 1];

    float a0 = 0.f, a1 = 0.f;
    for (int i = p0 + lane; i < p1; i += 32) {
        int r = csr[i];
        a0 += s0[r];
        a1 += s1[r];
    }
#pragma unroll
    for (int off = 16; off > 0; off >>= 1) {
        a0 += __shfl_down(a0, off, 32);
        a1 += __shfl_down(a1, off, 32);
    }
    if (lane == 0) {
        a0 += s0[n];  // self loop
        a1 += s1[n];
        float di = dinv[n];
        pr[n] = vbuf[H + 1] + di * a0;
        pc[n] = vbuf[H + 2] + di * a1;
    }
}

// ---------------------------------------------------------------------------
// Edge head, collapsed:
//   out[e] = c0 + sum_k relu(b1e[k] + ea[e].w1[:,k]) * v[k] + pr[row] + pc[col]
// 4 edges per thread for LDS-read reuse.
// ---------------------------------------------------------------------------
__global__ __launch_bounds__(256) void k_edge_final(const int* __restrict__ ei,
                                                    const float* __restrict__ ea,
                                                    const float* __restrict__ ew1,
                                                    const float* __restrict__ eb1,
                                                    const float* __restrict__ vbuf,
                                                    const float* __restrict__ pr,
                                                    const float* __restrict__ pc,
                                                    float* __restrict__ out) {
    __shared__ float w1t[H * F_EDGE];  // transposed: [k][m], column k contiguous
    __shared__ float b1s[H];
    __shared__ float vs[H];
    __shared__ float c0s;
    for (int i = threadIdx.x; i < H * F_EDGE; i += 256) {
        int k = i >> 4, m = i & 15;
        w1t[i] = ew1[m * H + k];
    }
    if (threadIdx.x < H) { b1s[threadIdx.x] = eb1[threadIdx.x]; vs[threadIdx.x] = vbuf[threadIdx.x]; }
    if (threadIdx.x == 0) c0s = vbuf[H];
    __syncthreads();

    long long t = (long long)blockIdx.x * 256 + threadIdx.x;
    long long e0 = t * 4;
    if (e0 >= N_EDGES) return;

    float a[4][F_EDGE];
#pragma unroll
    for (int i = 0; i < 4; i++) {
        const float4* p = (const float4*)(ea + (e0 + i) * F_EDGE);
#pragma unroll
        for (int j = 0; j < F_EDGE / 4; j++) {
            float4 v = p[j];
            a[i][4 * j] = v.x; a[i][4 * j + 1] = v.y; a[i][4 * j + 2] = v.z; a[i][4 * j + 3] = v.w;
        }
    }

    float c0 = c0s;
    float acc[4] = {c0, c0, c0, c0};
    const float4* w1v = (const float4*)w1t;
#pragma unroll
    for (int k = 0; k < H; k++) {
        float4 wa = w1v[k * 4 + 0];
        float4 wb = w1v[k * 4 + 1];
        float4 wc = w1v[k * 4 + 2];
        float4 wd = w1v[k * 4 + 3];
        float bk = b1s[k];
        float vk = vs[k];
#pragma unroll
        for (int i = 0; i < 4; i++) {
            float s = bk;
            s += a[i][0] * wa.x + a[i][1] * wa.y + a[i][2] * wa.z + a[i][3] * wa.w;
            s += a[i][4] * wb.x + a[i][5] * wb.y + a[i][6] * wb.z + a[i][7] * wb.w;
            s += a[i][8] * wc.x + a[i][9] * wc.y + a[i][10] * wc.z + a[i][11] * wc.w;
            s += a[i][12] * wd.x + a[i][13] * wd.y + a[i][14] * wd.z + a[i][15] * wd.w;
            acc[i] += (s > 0.f ? s : 0.f) * vk;
        }
    }

    float res[4];
#pragma unroll
    for (int i = 0; i < 4; i++) {
        int r = ei[e0 + i];
        int c = ei[N_EDGES + e0 + i];
        res[i] = acc[i] + pr[r] + pc[c];
    }
    *(float4*)(out + e0) = *(float4*)res;
}

// ---------------------------------------------------------------------------
extern "C" void kernel_launch(void* const* d_in, const int* in_sizes, int n_in,
                              void* d_out, int out_size, void* d_ws, size_t ws_size,
                              hipStream_t stream) {
    const float* x   = (const float*)d_in[0];
    const int*   ei  = (const int*)d_in[1];
    const float* ea  = (const float*)d_in[2];
    const float* W1  = (const float*)d_in[3];
    const float* b1  = (const float*)d_in[4];
    const float* W2  = (const float*)d_in[5];
    const float* b2  = (const float*)d_in[6];
    const float* ew1 = (const float*)d_in[7];
    const float* eb1 = (const float*)d_in[8];
    const float* ew2 = (const float*)d_in[9];
    const float* eb2 = (const float*)d_in[10];
    const float* fcw = (const float*)d_in[11];
    const float* fcb = (const float*)d_in[12];
    float* out = (float*)d_out;

    // Workspace layout
    int* cnt     = (int*)d_ws;                    // N
    int* ptr     = cnt + N_NODES;                 // N+1
    int* fillpos = ptr + N_NODES + 1;             // N
    int* bsum    = fillpos + N_NODES;             // 512
    int* bpre    = bsum + 512;                    // 512
    int* csr     = bpre + 512;                    // E
    float* dinv  = (float*)(csr + N_EDGES);       // N
    float* bufA  = dinv + N_NODES;                // N*PAD
    float* bufB  = bufA + (size_t)N_NODES * PAD;  // N*PAD
    float* s0    = bufB + (size_t)N_NODES * PAD;  // N
    float* s1    = s0 + N_NODES;                  // N
    float* pr    = s1 + N_NODES;                  // N
    float* pc    = pr + N_NODES;                  // N
    float* vbuf  = pc + N_NODES;                  // 32

    const int nb_edges = (N_EDGES + 255) / 256;       // 12500
    const int nb_ng    = (N_NODES * 32 + 255) / 256;  // 12500
    const int nb_e4    = (N_EDGES / 4 + 255) / 256;   // 3125

    // CSR build (int atomics only, once)
    k_zero<<<NB_NODES, 256, 0, stream>>>(cnt);
    k_count<<<nb_edges, 256, 0, stream>>>(ei, cnt);
    k_blocksum<<<NB_NODES, 256, 0, stream>>>(cnt, bsum);
    k_scan_bsums<<<1, 512, 0, stream>>>(bsum, bpre);
    k_scan_final<<<NB_NODES, 256, 0, stream>>>(cnt, bpre, ptr, fillpos);
    k_fill<<<nb_edges, 256, 0, stream>>>(ei, fillpos, csr);

    k_dinv<<<NB_NODES, 256, 0, stream>>>(cnt, dinv);
    k_prep<<<1, 64, 0, stream>>>(ew2, eb2, b2, fcw, fcb, vbuf);

    // Layer 1 (pull)
    k_l1pre<<<NB_NODES, 256, 0, stream>>>(x, W1, dinv, bufA);
    k_gather27<<<nb_ng, 256, 0, stream>>>(ptr, csr, bufA, bufB);

    // Layer 2 collapsed to per-node scalars (pull)
    k_l1post<<<NB_NODES, 256, 0, stream>>>(W2, b1, fcw, dinv, bufB, s0, s1);
    k_pull2<<<nb_ng, 256, 0, stream>>>(ptr, csr, s0, s1, dinv, vbuf, pr, pc);

    // Edge head
    k_edge_final<<<nb_e4, 256, 0, stream>>>(ei, ea, ew1, eb1, vbuf, pr, pc, out);
}